// Round 7
// baseline (296.499 us; speedup 1.0000x reference)
//
#include <hip/hip_runtime.h>

#define S_  512
#define B_  256
#define NIN 180

// ---- DPP ctrl encodings (verified on HW in r5/r6) ----
#define QP_X1 0xB1   // quad_perm -> lane i reads i^1
#define QP_X2 0x4E   // i^2
#define QP_X3 0x1B   // i^3
#define ROR4  0x124  // row rotate 4 (== xor4 on 8-periodic data)
#define ROR8  0x128  // row rotate 8 (== xor8 within each 16-lane row)

template<int CTRL>
__device__ __forceinline__ float dppf(float x) {
    return __uint_as_float((unsigned)__builtin_amdgcn_update_dpp(
        0, (int)__float_as_uint(x), CTRL, 0xF, 0xF, true));
}

// ======================= Kernel A: input GEMM =======================
// Same verified layout as r6:
// xg[(s*64 + b/4)*128 + (q>=2)*64 + (b&3)*16 + (q&1)*8 + (g&7)] =
//   s(g) * (x[s,b,:]·w_ih0[g,:] + b_ih0[g]+b_hh0[g]),  q = g>>3
// New: depth-4 register prefetch ring to hide ~900cy HBM latency.
__global__ __launch_bounds__(256) void xg_gemm(
    const float* __restrict__ x, const float* __restrict__ w,
    const float* __restrict__ bi, const float* __restrict__ bh,
    float* __restrict__ xg)
{
    __shared__ float wt[NIN][32];   // transposed + pre-scaled by s(g)
    __shared__ float bias[32];
    const int tid = threadIdx.x;
    for (int idx = tid; idx < NIN * 32; idx += 256) {
        int g = idx / NIN, i = idx - g * NIN;
        float s = ((g >> 3) == 2) ? -2.8853900817779268f : -1.4426950408889634f;
        wt[i][g] = s * w[idx];
    }
    if (tid < 32) {
        float s = ((tid >> 3) == 2) ? -2.8853900817779268f : -1.4426950408889634f;
        bias[tid] = s * (bi[tid] + bh[tid]);
    }
    __syncthreads();

    const int rg   = tid >> 3;        // 0..31 -> 4 rows each
    const int gq   = tid & 7;         // gate quad
    const int s    = blockIdx.x >> 1;
    const int half = blockIdx.x & 1;
    const int b0   = half * 128 + rg * 4;
    const float* xr = x + ((size_t)s * B_ + b0) * NIN;

    float4 acc[4];
    #pragma unroll
    for (int rr = 0; rr < 4; ++rr) acc[rr] = float4{0.f, 0.f, 0.f, 0.f};

    float4 xb[4][4];   // [depth][row], all indices static after inlining
    #pragma unroll
    for (int d = 0; d < 4; ++d)
        #pragma unroll
        for (int rr = 0; rr < 4; ++rr)
            xb[d][rr] = *(const float4*)(xr + (size_t)rr * NIN + 4 * d);

    auto GSTEP = [&](int ii, int d, bool pref) {
        #pragma unroll
        for (int e = 0; e < 4; ++e) {
            float4 wv = *(const float4*)&wt[4 * ii + e][gq * 4];
            #pragma unroll
            for (int rr = 0; rr < 4; ++rr) {
                float xe = (e == 0) ? xb[d][rr].x : (e == 1) ? xb[d][rr].y
                         : (e == 2) ? xb[d][rr].z : xb[d][rr].w;
                acc[rr].x = __builtin_fmaf(xe, wv.x, acc[rr].x);
                acc[rr].y = __builtin_fmaf(xe, wv.y, acc[rr].y);
                acc[rr].z = __builtin_fmaf(xe, wv.z, acc[rr].z);
                acc[rr].w = __builtin_fmaf(xe, wv.w, acc[rr].w);
            }
        }
        if (pref) {
            #pragma unroll
            for (int rr = 0; rr < 4; ++rr)
                xb[d][rr] = *(const float4*)(xr + (size_t)rr * NIN + 4 * (ii + 4));
        }
    };

    for (int ii = 0; ii < 40; ii += 4) {
        GSTEP(ii + 0, 0, true);
        GSTEP(ii + 1, 1, true);
        GSTEP(ii + 2, 2, true);
        GSTEP(ii + 3, 3, true);
    }
    GSTEP(40, 0, true);    // loads ii=44 into slot 0
    GSTEP(41, 1, false);
    GSTEP(42, 2, false);
    GSTEP(43, 3, false);
    GSTEP(44, 0, false);

    float4 bv = *(const float4*)&bias[gq * 4];
    const int g0  = 4 * gq;
    const int q   = g0 >> 3;
    const int j0  = g0 & 7;
    const int off = (q >> 1) * 64 + (q & 1) * 8 + j0;
    #pragma unroll
    for (int rr = 0; rr < 4; ++rr) {
        int b = b0 + rr;
        int bidc = b >> 2, cc = b & 3;
        float4 o = {acc[rr].x + bv.x, acc[rr].y + bv.y,
                    acc[rr].z + bv.z, acc[rr].w + bv.w};
        size_t addr = ((size_t)s * 64 + bidc) * 128 + off + cc * 16;
        *(float4*)(xg + addr) = o;
    }
}

// ======================= Kernel B: fused scan =======================
// 16 lanes/chain, 4 chain-slots/wave, and 2 TEMPORALLY INTERLEAVED chains
// (P,Q) per slot: P and Q step alternately in one instruction stream so
// each fills the other's dependency stalls. Zero LDS-pipe ops (pure DPP).
// chainP = 4*bid+cc, chainQ = chainP+128. Pipeline per chain:
// layer0(u) || layer1(u-1) || proj(u-2).
__global__ __launch_bounds__(64) void lstm_scan(
    const float* __restrict__ xg,
    const float* __restrict__ w_hh0,
    const float* __restrict__ w_ih1, const float* __restrict__ w_hh1,
    const float* __restrict__ b_ih1, const float* __restrict__ b_hh1,
    const float* __restrict__ w_reg, const float* __restrict__ b_reg,
    float* __restrict__ out)
{
    const int lt = threadIdx.x;
    const int j  = lt & 7;
    const int b3 = (lt >> 3) & 1;
    const int cc = lt >> 4;            // 0..3 chain-slot within wave
    const bool b3z = (b3 == 0);
    const bool isl = (j == 0);
    const int bid = blockIdx.x;        // 0..31

    const int gA = b3 * 8 + j;         // i or f  (sigmoid)
    const int gB = (2 + b3) * 8 + j;   // g or o  (tanh / sigmoid)

    const float sSig  = -1.4426950408889634f;
    const float sTanh = -2.8853900817779268f;
    const float sB = b3z ? sTanh : sSig;
    const float aB = b3z ? 2.0f : 1.0f;
    const float bB = b3z ? -1.0f : 0.0f;

    float w0A[8], w0B[8], wi1A[8], wi1B[8], wh1A[8], wh1B[8], wrl[8];
    #pragma unroll
    for (int m = 0; m < 8; ++m) {
        int k = j ^ m;
        w0A[m]  = sSig * w_hh0[gA * 8 + k];
        w0B[m]  = sB   * w_hh0[gB * 8 + k];
        wi1A[m] = sSig * w_ih1[gA * 8 + k];
        wi1B[m] = sB   * w_ih1[gB * 8 + k];
        wh1A[m] = sSig * w_hh1[gA * 8 + k];
        wh1B[m] = sB   * w_hh1[gB * 8 + k];
        wrl[m]  = w_reg[b3 * 8 + k];
    }
    const float b1A = sSig * (b_ih1[gA] + b_hh1[gA]);
    const float b1B = sB   * (b_ih1[gB] + b_hh1[gB]);
    const float br  = b_reg[b3];

    auto sig = [](float a) {
        return __builtin_amdgcn_rcpf(1.0f + __builtin_amdgcn_exp2f(a));
    };
    auto actB = [&](float a) {
        return __builtin_fmaf(aB, __builtin_amdgcn_rcpf(1.0f + __builtin_amdgcn_exp2f(a)), bB);
    };
    auto tanhc = [](float c) {
        return __builtin_fmaf(2.0f, __builtin_amdgcn_rcpf(
            1.0f + __builtin_amdgcn_exp2f(-2.8853900817779268f * c)), -1.0f);
    };
    auto ROTS = [&](float h, float* r) {
        r[0] = h;
        r[1] = dppf<QP_X1>(h);
        r[2] = dppf<QP_X2>(h);
        r[3] = dppf<QP_X3>(h);
        r[4] = dppf<ROR4>(h);
        r[5] = dppf<QP_X1>(r[4]);
        r[6] = dppf<QP_X2>(r[4]);
        r[7] = dppf<QP_X3>(r[4]);
    };
    auto COMBINE2 = [&](float tA, float tB, float& c, float& h) {
        float m  = tA * tB;
        float mr = dppf<ROR8>(m);
        float fa = dppf<ROR8>(tA);
        float ob = dppf<ROR8>(tB);
        float ig = b3z ? m  : mr;
        float f  = b3z ? fa : tA;
        float o  = b3z ? ob : tB;
        c = __builtin_fmaf(f, c, ig);
        h = o * tanhc(c);
    };

    // ---- per-chain state ----
    float h0P = 0.f, h1P = 0.f, c0P = 0.f, c1P = 0.f;
    float h0Q = 0.f, h1Q = 0.f, c0Q = 0.f, c1Q = 0.f;

    const float* xbP = xg + (size_t)bid * 128 + lt;
    const float* xbQ = xg + (size_t)(bid + 32) * 128 + lt;
    float PrA[4], PrB[4], QrA[4], QrB[4];    // depth-4 prefetch rings
    #pragma unroll
    for (int d = 0; d < 4; ++d) {
        PrA[d] = xbP[(size_t)d * 8192];
        PrB[d] = xbP[(size_t)d * 8192 + 64];
        QrA[d] = xbQ[(size_t)d * 8192];
        QrB[d] = xbQ[(size_t)d * 8192 + 64];
    }
    const float* xpP = xbP + (size_t)4 * 8192;
    const float* xpQ = xbQ + (size_t)4 * 8192;
    float* opP = out + (size_t)(bid * 4 + cc) * 2 + b3;
    float* opQ = out + (size_t)(bid * 4 + cc + 128) * 2 + b3;

    auto STEP = [&](float& h0p, float& h1p, float& c0, float& c1,
                    float& xrA, float& xrB, const float*& xp, float*& op,
                    bool l1on, bool doproj, bool pref) {
        float r0[8], r1[8];
        ROTS(h0p, r0);      // h0(u-1)
        ROTS(h1p, r1);      // h1(u-2)
        float a0A = xrA, a0B = xrB;
        if (pref) { xrA = xp[0]; xrB = xp[64]; xp += 8192; }
        #pragma unroll
        for (int m = 0; m < 8; ++m) {
            a0A = __builtin_fmaf(w0A[m], r0[m], a0A);
            a0B = __builtin_fmaf(w0B[m], r0[m], a0B);
        }
        float tA0 = sig(a0A), tB0 = actB(a0B);

        float a1A = b1A, a1B = b1B;
        float s1A = wh1A[0] * r1[0], s1B = wh1B[0] * r1[0];
        #pragma unroll
        for (int m = 0; m < 8; ++m) {
            a1A = __builtin_fmaf(wi1A[m], r0[m], a1A);
            a1B = __builtin_fmaf(wi1B[m], r0[m], a1B);
        }
        #pragma unroll
        for (int m = 1; m < 8; ++m) {
            s1A = __builtin_fmaf(wh1A[m], r1[m], s1A);
            s1B = __builtin_fmaf(wh1B[m], r1[m], s1B);
        }
        float tA1 = sig(a1A + s1A), tB1 = actB(a1B + s1B);

        if (doproj) {
            float p = br;
            #pragma unroll
            for (int m = 0; m < 8; ++m) p = __builtin_fmaf(wrl[m], r1[m], p);
            if (isl) *op = p;
            op += B_ * 2;
        }
        COMBINE2(tA0, tB0, c0, h0p);
        if (l1on) COMBINE2(tA1, tB1, c1, h1p);
    };

    // one pipeline step u for BOTH chains (interleaved instruction streams)
    #define PAIR(d, L1, PRJ, PREF)                                              \
        STEP(h0P, h1P, c0P, c1P, PrA[d], PrB[d], xpP, opP, L1, PRJ, PREF);      \
        STEP(h0Q, h1Q, c0Q, c1Q, QrA[d], QrB[d], xpQ, opQ, L1, PRJ, PREF);

    // prologue u=0..3
    PAIR(0, false, false, true)
    PAIR(1, true,  false, true)
    PAIR(2, true,  true,  true)
    PAIR(3, true,  true,  true)
    // main u=4..503
    for (int tb = 4; tb < 504; tb += 4) {
        PAIR(0, true, true, true)
        PAIR(1, true, true, true)
        PAIR(2, true, true, true)
        PAIR(3, true, true, true)
    }
    // epi1 u=504..507 (prefetch loads rows 508..511)
    PAIR(0, true, true, true)
    PAIR(1, true, true, true)
    PAIR(2, true, true, true)
    PAIR(3, true, true, true)
    // epi2 u=508..511 (no prefetch)
    PAIR(0, true, true, false)
    PAIR(1, true, true, false)
    PAIR(2, true, true, false)
    PAIR(3, true, true, false)
    #undef PAIR

    // tail per chain: layer1(511) + proj(510), then proj(511)
    auto TAIL = [&](float& h0p, float& h1p, float& c1, float*& op) {
        float r0[8], r1[8];
        ROTS(h0p, r0);      // h0(511)
        ROTS(h1p, r1);      // h1(510)
        float a1A = b1A, a1B = b1B;
        #pragma unroll
        for (int m = 0; m < 8; ++m) {
            a1A = __builtin_fmaf(wi1A[m], r0[m], a1A);
            a1B = __builtin_fmaf(wi1B[m], r0[m], a1B);
        }
        #pragma unroll
        for (int m = 0; m < 8; ++m) {
            a1A = __builtin_fmaf(wh1A[m], r1[m], a1A);
            a1B = __builtin_fmaf(wh1B[m], r1[m], a1B);
        }
        float tA1 = sig(a1A), tB1 = actB(a1B);

        float p = br;
        #pragma unroll
        for (int m = 0; m < 8; ++m) p = __builtin_fmaf(wrl[m], r1[m], p);
        if (isl) *op = p;           // row 510
        op += B_ * 2;

        COMBINE2(tA1, tB1, c1, h1p);   // h1(511)
        float r2[8];
        ROTS(h1p, r2);
        float p2 = br;
        #pragma unroll
        for (int m = 0; m < 8; ++m) p2 = __builtin_fmaf(wrl[m], r2[m], p2);
        if (isl) *op = p2;          // row 511
    };
    TAIL(h0P, h1P, c1P, opP);
    TAIL(h0Q, h1Q, c1Q, opQ);
}

extern "C" void kernel_launch(void* const* d_in, const int* in_sizes, int n_in,
                              void* d_out, int out_size, void* d_ws, size_t ws_size,
                              hipStream_t stream) {
    (void)in_sizes; (void)n_in; (void)out_size; (void)ws_size;
    const float* x     = (const float*)d_in[0];
    const float* w_ih0 = (const float*)d_in[1];
    const float* w_hh0 = (const float*)d_in[2];
    const float* b_ih0 = (const float*)d_in[3];
    const float* b_hh0 = (const float*)d_in[4];
    const float* w_ih1 = (const float*)d_in[5];
    const float* w_hh1 = (const float*)d_in[6];
    const float* b_ih1 = (const float*)d_in[7];
    const float* b_hh1 = (const float*)d_in[8];
    const float* w_reg = (const float*)d_in[9];
    const float* b_reg = (const float*)d_in[10];
    float* out = (float*)d_out;
    float* xg  = (float*)d_ws;   // 512*64*128*4 = 16 MB scratch

    xg_gemm<<<1024, 256, 0, stream>>>(x, w_ih0, b_ih0, b_hh0, xg);
    lstm_scan<<<32, 64, 0, stream>>>(xg, w_hh0, w_ih1, w_hh1, b_ih1, b_hh1,
                                     w_reg, b_reg, out);
}

// Round 8
// 175.635 us; speedup vs baseline: 1.6882x; 1.6882x over previous
//
#include <hip/hip_runtime.h>

#define S_  512
#define B_  256
#define NIN 180

// ---- DPP ctrl encodings (verified on HW in r5/r6) ----
#define QP_X1 0xB1   // quad_perm -> lane i reads i^1
#define QP_X2 0x4E   // i^2
#define QP_X3 0x1B   // i^3
#define ROR4  0x124  // row rotate 4 (== xor4 on 8-periodic data)
#define ROR8  0x128  // row rotate 8 (== xor8 within each 16-lane row)

template<int CTRL>
__device__ __forceinline__ float dppf(float x) {
    return __uint_as_float((unsigned)__builtin_amdgcn_update_dpp(
        0, (int)__float_as_uint(x), CTRL, 0xF, 0xF, true));
}

// ======================= Kernel A: input GEMM =======================
// Verified layout (r6):
// xg[(s*64 + b/4)*128 + (q>=2)*64 + (b&3)*16 + (q&1)*8 + (g&7)] =
//   s(g) * (x[s,b,:]·w_ih0[g,:] + b_ih0[g]+b_hh0[g]),  q = g>>3
// 8 rows/thread (halves LDS-pipe traffic), depth-3 prefetch ring.
__global__ __launch_bounds__(256, 2) void xg_gemm(
    const float* __restrict__ x, const float* __restrict__ w,
    const float* __restrict__ bi, const float* __restrict__ bh,
    float* __restrict__ xg)
{
    __shared__ float wt[NIN][32];   // transposed + pre-scaled by s(g)
    __shared__ float bias[32];
    const int tid = threadIdx.x;
    for (int idx = tid; idx < NIN * 32; idx += 256) {
        int g = idx / NIN, i = idx - g * NIN;
        float s = ((g >> 3) == 2) ? -2.8853900817779268f : -1.4426950408889634f;
        wt[i][g] = s * w[idx];
    }
    if (tid < 32) {
        float s = ((tid >> 3) == 2) ? -2.8853900817779268f : -1.4426950408889634f;
        bias[tid] = s * (bi[tid] + bh[tid]);
    }
    __syncthreads();

    const int rg = tid >> 3;          // 0..31 -> 8 rows each
    const int gq = tid & 7;           // gate quad
    const int s  = blockIdx.x;        // grid 512 = S
    const int b0 = rg * 8;
    const float* xr = x + ((size_t)s * B_ + b0) * NIN;

    float4 acc[8];
    #pragma unroll
    for (int rr = 0; rr < 8; ++rr) acc[rr] = float4{0.f, 0.f, 0.f, 0.f};

    float4 xb[3][8];   // [depth][row], static indices everywhere
    #pragma unroll
    for (int d = 0; d < 3; ++d)
        #pragma unroll
        for (int rr = 0; rr < 8; ++rr)
            xb[d][rr] = *(const float4*)(xr + (size_t)rr * NIN + 4 * d);

    auto GSTEP = [&](int ii, int d, bool pref) {
        float4 xn[8];
        if (pref) {   // issue loads for ii+3 FIRST (max in-flight time)
            #pragma unroll
            for (int rr = 0; rr < 8; ++rr)
                xn[rr] = *(const float4*)(xr + (size_t)rr * NIN + 4 * (ii + 3));
        }
        #pragma unroll
        for (int e = 0; e < 4; ++e) {
            float4 wv = *(const float4*)&wt[4 * ii + e][gq * 4];
            #pragma unroll
            for (int rr = 0; rr < 8; ++rr) {
                float xe = (e == 0) ? xb[d][rr].x : (e == 1) ? xb[d][rr].y
                         : (e == 2) ? xb[d][rr].z : xb[d][rr].w;
                acc[rr].x = __builtin_fmaf(xe, wv.x, acc[rr].x);
                acc[rr].y = __builtin_fmaf(xe, wv.y, acc[rr].y);
                acc[rr].z = __builtin_fmaf(xe, wv.z, acc[rr].z);
                acc[rr].w = __builtin_fmaf(xe, wv.w, acc[rr].w);
            }
        }
        if (pref) {
            #pragma unroll
            for (int rr = 0; rr < 8; ++rr) xb[d][rr] = xn[rr];
        }
    };

    for (int r = 0; r < 14; ++r) {
        GSTEP(3 * r + 0, 0, true);
        GSTEP(3 * r + 1, 1, true);
        GSTEP(3 * r + 2, 2, true);
    }
    GSTEP(42, 0, false);
    GSTEP(43, 1, false);
    GSTEP(44, 2, false);

    float4 bv = *(const float4*)&bias[gq * 4];
    const int g0  = 4 * gq;
    const int q   = g0 >> 3;
    const int j0  = g0 & 7;
    const int off = (q >> 1) * 64 + (q & 1) * 8 + j0;
    #pragma unroll
    for (int rr = 0; rr < 8; ++rr) {
        int b = b0 + rr;
        float4 o = {acc[rr].x + bv.x, acc[rr].y + bv.y,
                    acc[rr].z + bv.z, acc[rr].w + bv.w};
        size_t addr = ((size_t)s * 64 + (b >> 2)) * 128 + off + (b & 3) * 16;
        *(float4*)(xg + addr) = o;
    }
}

// ======================= Kernel B: fused scan =======================
// 16 lanes/chain, 4 chains/wave (spatial), 64 waves. Zero LDS-pipe ops.
// launch_bounds(64,1): schedule for 1 wave/EU -> fill latency, not save regs.
// Matvecs split into 2-way partial chains for ILP; trans ops batched.
__global__ __launch_bounds__(64, 1) void lstm_scan(
    const float* __restrict__ xg,
    const float* __restrict__ w_hh0,
    const float* __restrict__ w_ih1, const float* __restrict__ w_hh1,
    const float* __restrict__ b_ih1, const float* __restrict__ b_hh1,
    const float* __restrict__ w_reg, const float* __restrict__ b_reg,
    float* __restrict__ out)
{
    const int lt = threadIdx.x;
    const int j  = lt & 7;
    const int b3 = (lt >> 3) & 1;
    const int cc = lt >> 4;            // 0..3 chain-slot
    const bool b3z = (b3 == 0);
    const bool isl = (j == 0);
    const int bid   = blockIdx.x;      // 0..63
    const int chain = bid * 4 + cc;

    const int gA = b3 * 8 + j;         // i or f  (sigmoid)
    const int gB = (2 + b3) * 8 + j;   // g or o  (tanh / sigmoid)

    const float sSig  = -1.4426950408889634f;
    const float sTanh = -2.8853900817779268f;
    const float sB = b3z ? sTanh : sSig;
    const float aB = b3z ? 2.0f : 1.0f;
    const float bB = b3z ? -1.0f : 0.0f;

    float w0A[8], w0B[8], wi1A[8], wi1B[8], wh1A[8], wh1B[8], wrl[8];
    #pragma unroll
    for (int m = 0; m < 8; ++m) {
        int k = j ^ m;
        w0A[m]  = sSig * w_hh0[gA * 8 + k];
        w0B[m]  = sB   * w_hh0[gB * 8 + k];
        wi1A[m] = sSig * w_ih1[gA * 8 + k];
        wi1B[m] = sB   * w_ih1[gB * 8 + k];
        wh1A[m] = sSig * w_hh1[gA * 8 + k];
        wh1B[m] = sB   * w_hh1[gB * 8 + k];
        wrl[m]  = w_reg[b3 * 8 + k];
    }
    const float b1A = sSig * (b_ih1[gA] + b_hh1[gA]);
    const float b1B = sB   * (b_ih1[gB] + b_hh1[gB]);
    const float br  = b_reg[b3];

    auto tanhc = [](float c) {
        return __builtin_fmaf(2.0f, __builtin_amdgcn_rcpf(
            1.0f + __builtin_amdgcn_exp2f(-2.8853900817779268f * c)), -1.0f);
    };
    auto COMBINE2 = [&](float tA, float tB, float& c, float& h) {
        float m  = tA * tB;
        float mr = dppf<ROR8>(m);
        float fa = dppf<ROR8>(tA);
        float ob = dppf<ROR8>(tB);
        float ig = b3z ? m  : mr;
        float f  = b3z ? fa : tA;
        float o  = b3z ? ob : tB;
        c = __builtin_fmaf(f, c, ig);
        h = o * tanhc(c);
    };

    float h0p = 0.f, h1p = 0.f, c0 = 0.f, c1 = 0.f;

    const float* xb = xg + (size_t)bid * 128 + lt;
    float xqA[8], xqB[8];
    #pragma unroll
    for (int k = 0; k < 8; ++k) {
        xqA[k] = xb[(size_t)k * 8192];
        xqB[k] = xb[(size_t)k * 8192 + 64];
    }
    const float* xp = xb + (size_t)8 * 8192;
    float* op = out + (size_t)chain * 2 + b3;

    auto STEP = [&](float& xrA, float& xrB, bool l1on, bool doproj, bool pref) {
        // loads first (independent of everything)
        float nA = 0.f, nB = 0.f;
        if (pref) { nA = xp[0]; nB = xp[64]; xp += 8192; }

        // both ROTS interleaved
        float r0[8], r1[8];
        r0[0] = h0p;              r1[0] = h1p;
        r0[1] = dppf<QP_X1>(h0p); r1[1] = dppf<QP_X1>(h1p);
        r0[2] = dppf<QP_X2>(h0p); r1[2] = dppf<QP_X2>(h1p);
        r0[3] = dppf<QP_X3>(h0p); r1[3] = dppf<QP_X3>(h1p);
        r0[4] = dppf<ROR4>(h0p);  r1[4] = dppf<ROR4>(h1p);
        r0[5] = dppf<QP_X1>(r0[4]); r1[5] = dppf<QP_X1>(r1[4]);
        r0[6] = dppf<QP_X2>(r0[4]); r1[6] = dppf<QP_X2>(r1[4]);
        r0[7] = dppf<QP_X3>(r0[4]); r1[7] = dppf<QP_X3>(r1[4]);

        // 14 independent partial chains (depth 4 each)
        float a0A0 = __builtin_fmaf(w0A[0], r0[0], xrA);
        float a0B0 = __builtin_fmaf(w0B[0], r0[0], xrB);
        float a1A0 = __builtin_fmaf(wi1A[0], r0[0], b1A);
        float a1B0 = __builtin_fmaf(wi1B[0], r0[0], b1B);
        float s1A0 = wh1A[0] * r1[0];
        float s1B0 = wh1B[0] * r1[0];
        float p0   = __builtin_fmaf(wrl[0], r1[0], br);
        float a0A1 = w0A[4] * r0[4];
        float a0B1 = w0B[4] * r0[4];
        float a1A1 = wi1A[4] * r0[4];
        float a1B1 = wi1B[4] * r0[4];
        float s1A1 = wh1A[4] * r1[4];
        float s1B1 = wh1B[4] * r1[4];
        float p1   = wrl[4] * r1[4];
        #pragma unroll
        for (int m = 1; m < 4; ++m) {
            a0A0 = __builtin_fmaf(w0A[m], r0[m], a0A0);
            a0B0 = __builtin_fmaf(w0B[m], r0[m], a0B0);
            a1A0 = __builtin_fmaf(wi1A[m], r0[m], a1A0);
            a1B0 = __builtin_fmaf(wi1B[m], r0[m], a1B0);
            s1A0 = __builtin_fmaf(wh1A[m], r1[m], s1A0);
            s1B0 = __builtin_fmaf(wh1B[m], r1[m], s1B0);
            p0   = __builtin_fmaf(wrl[m], r1[m], p0);
            a0A1 = __builtin_fmaf(w0A[m + 4], r0[m + 4], a0A1);
            a0B1 = __builtin_fmaf(w0B[m + 4], r0[m + 4], a0B1);
            a1A1 = __builtin_fmaf(wi1A[m + 4], r0[m + 4], a1A1);
            a1B1 = __builtin_fmaf(wi1B[m + 4], r0[m + 4], a1B1);
            s1A1 = __builtin_fmaf(wh1A[m + 4], r1[m + 4], s1A1);
            s1B1 = __builtin_fmaf(wh1B[m + 4], r1[m + 4], s1B1);
            p1   = __builtin_fmaf(wrl[m + 4], r1[m + 4], p1);
        }
        if (pref) { xrA = nA; xrB = nB; }

        float a0A = a0A0 + a0A1;
        float a0B = a0B0 + a0B1;
        float a1A = (a1A0 + a1A1) + (s1A0 + s1A1);
        float a1B = (a1B0 + a1B1) + (s1B0 + s1B1);

        // batched transcendentals: 4 exp2, then 4 rcp
        float eA0 = __builtin_amdgcn_exp2f(a0A);
        float eB0 = __builtin_amdgcn_exp2f(a0B);
        float eA1 = __builtin_amdgcn_exp2f(a1A);
        float eB1 = __builtin_amdgcn_exp2f(a1B);
        float tA0 = __builtin_amdgcn_rcpf(1.0f + eA0);
        float tB0 = __builtin_fmaf(aB, __builtin_amdgcn_rcpf(1.0f + eB0), bB);
        float tA1 = __builtin_amdgcn_rcpf(1.0f + eA1);
        float tB1 = __builtin_fmaf(aB, __builtin_amdgcn_rcpf(1.0f + eB1), bB);

        if (doproj) {
            if (isl) *op = p0 + p1;
            op += B_ * 2;
        }
        COMBINE2(tA0, tB0, c0, h0p);              // -> h0(u)
        if (l1on) COMBINE2(tA1, tB1, c1, h1p);    // -> h1(u-1)
    };

    // prologue u=0..7
    #pragma unroll
    for (int k = 0; k < 8; ++k) STEP(xqA[k], xqB[k], k > 0, k >= 2, true);
    // main u=8..503
    for (int tb = 8; tb < 504; tb += 8) {
        #pragma unroll
        for (int k = 0; k < 8; ++k) STEP(xqA[k], xqB[k], true, true, true);
    }
    // epilogue u=504..511 (no prefetch)
    #pragma unroll
    for (int k = 0; k < 8; ++k) STEP(xqA[k], xqB[k], true, true, false);

    // tail: layer1(511) + proj(510), then proj(511)
    {
        float r0[8], r1[8];
        r0[0] = h0p;              r1[0] = h1p;
        r0[1] = dppf<QP_X1>(h0p); r1[1] = dppf<QP_X1>(h1p);
        r0[2] = dppf<QP_X2>(h0p); r1[2] = dppf<QP_X2>(h1p);
        r0[3] = dppf<QP_X3>(h0p); r1[3] = dppf<QP_X3>(h1p);
        r0[4] = dppf<ROR4>(h0p);  r1[4] = dppf<ROR4>(h1p);
        r0[5] = dppf<QP_X1>(r0[4]); r1[5] = dppf<QP_X1>(r1[4]);
        r0[6] = dppf<QP_X2>(r0[4]); r1[6] = dppf<QP_X2>(r1[4]);
        r0[7] = dppf<QP_X3>(r0[4]); r1[7] = dppf<QP_X3>(r1[4]);

        float a1A = b1A, a1B = b1B, p = br;
        #pragma unroll
        for (int m = 0; m < 8; ++m) {
            a1A = __builtin_fmaf(wi1A[m], r0[m], a1A);
            a1B = __builtin_fmaf(wi1B[m], r0[m], a1B);
        }
        #pragma unroll
        for (int m = 0; m < 8; ++m) {
            a1A = __builtin_fmaf(wh1A[m], r1[m], a1A);
            a1B = __builtin_fmaf(wh1B[m], r1[m], a1B);
            p   = __builtin_fmaf(wrl[m], r1[m], p);
        }
        float tA1 = __builtin_amdgcn_rcpf(1.0f + __builtin_amdgcn_exp2f(a1A));
        float tB1 = __builtin_fmaf(aB,
            __builtin_amdgcn_rcpf(1.0f + __builtin_amdgcn_exp2f(a1B)), bB);

        if (isl) *op = p;           // row 510
        op += B_ * 2;

        COMBINE2(tA1, tB1, c1, h1p);   // h1(511)
        float r2[8];
        r2[0] = h1p;
        r2[1] = dppf<QP_X1>(h1p);
        r2[2] = dppf<QP_X2>(h1p);
        r2[3] = dppf<QP_X3>(h1p);
        r2[4] = dppf<ROR4>(h1p);
        r2[5] = dppf<QP_X1>(r2[4]);
        r2[6] = dppf<QP_X2>(r2[4]);
        r2[7] = dppf<QP_X3>(r2[4]);
        float p2 = br;
        #pragma unroll
        for (int m = 0; m < 8; ++m) p2 = __builtin_fmaf(wrl[m], r2[m], p2);
        if (isl) *op = p2;          // row 511
    }
}

extern "C" void kernel_launch(void* const* d_in, const int* in_sizes, int n_in,
                              void* d_out, int out_size, void* d_ws, size_t ws_size,
                              hipStream_t stream) {
    (void)in_sizes; (void)n_in; (void)out_size; (void)ws_size;
    const float* x     = (const float*)d_in[0];
    const float* w_ih0 = (const float*)d_in[1];
    const float* w_hh0 = (const float*)d_in[2];
    const float* b_ih0 = (const float*)d_in[3];
    const float* b_hh0 = (const float*)d_in[4];
    const float* w_ih1 = (const float*)d_in[5];
    const float* w_hh1 = (const float*)d_in[6];
    const float* b_ih1 = (const float*)d_in[7];
    const float* b_hh1 = (const float*)d_in[8];
    const float* w_reg = (const float*)d_in[9];
    const float* b_reg = (const float*)d_in[10];
    float* out = (float*)d_out;
    float* xg  = (float*)d_ws;   // 512*64*128*4 = 16 MB scratch

    xg_gemm<<<512, 256, 0, stream>>>(x, w_ih0, b_ih0, b_hh0, xg);
    lstm_scan<<<64, 64, 0, stream>>>(xg, w_hh0, w_ih1, w_hh1, b_ih1, b_hh1,
                                     w_reg, b_reg, out);
}

// Round 9
// 150.659 us; speedup vs baseline: 1.9680x; 1.1658x over previous
//
#include <hip/hip_runtime.h>

#define S_  512
#define B_  256
#define NIN 180

typedef float v2 __attribute__((ext_vector_type(2)));

#define SSIG  -1.4426950408889634f
#define STANH -2.8853900817779268f

// ---- DPP ctrl encodings (verified on HW r5-r8) ----
#define QP_X1 0xB1
#define QP_X2 0x4E
#define QP_X3 0x1B
#define ROR4  0x124
#define ROR8  0x128

template<int CTRL>
__device__ __forceinline__ float dppf(float x) {
    return __uint_as_float((unsigned)__builtin_amdgcn_update_dpp(
        0, (int)__float_as_uint(x), CTRL, 0xF, 0xF, true));
}

// ======================= Kernel A: input GEMM =======================
// xg2[(((s*64 + b/4)*64) + (b&3)*16 + (q&1)*8 + (g&7))*2 + (q>>1)] =
//   s(g)*(x[s,b,:]·w_ih0[g,:] + b_ih0[g]+b_hh0[g]),  q = g>>3
// 2048 blocks (s,quarter-batch), 2 rows/thread, depth-2 ring -> high TLP.
__global__ __launch_bounds__(256) void xg_gemm(
    const float* __restrict__ x, const float* __restrict__ w,
    const float* __restrict__ bi, const float* __restrict__ bh,
    float* __restrict__ xg2)
{
    __shared__ float wt[NIN][32];
    __shared__ float bias[32];
    const int tid = threadIdx.x;
    for (int idx = tid; idx < NIN * 32; idx += 256) {
        int g = idx / NIN, i = idx - g * NIN;
        float sc = ((g >> 3) == 2) ? STANH : SSIG;
        wt[i][g] = sc * w[idx];
    }
    if (tid < 32) {
        float sc = ((tid >> 3) == 2) ? STANH : SSIG;
        bias[tid] = sc * (bi[tid] + bh[tid]);
    }
    __syncthreads();

    const int rp = tid >> 3;
    const int gq = tid & 7;
    const int s  = blockIdx.x >> 2;
    const int b0 = (blockIdx.x & 3) * 64 + rp * 2;
    const float* xr = x + ((size_t)s * B_ + b0) * NIN;

    float4 acc0 = {0.f,0.f,0.f,0.f}, acc1 = {0.f,0.f,0.f,0.f};
    float4 r0v[2], r1v[2];
    r0v[0] = *(const float4*)(xr + 0);   r1v[0] = *(const float4*)(xr + NIN + 0);
    r0v[1] = *(const float4*)(xr + 4);   r1v[1] = *(const float4*)(xr + NIN + 4);

    #pragma unroll
    for (int ii = 0; ii < 45; ++ii) {
        const int sl = ii & 1;
        float4 xa = r0v[sl], xb = r1v[sl];
        if (ii < 43) {
            r0v[sl] = *(const float4*)(xr + 4 * (ii + 2));
            r1v[sl] = *(const float4*)(xr + NIN + 4 * (ii + 2));
        }
        #pragma unroll
        for (int e = 0; e < 4; ++e) {
            float4 wv = *(const float4*)&wt[4 * ii + e][gq * 4];
            float xe = (e == 0) ? xa.x : (e == 1) ? xa.y : (e == 2) ? xa.z : xa.w;
            float xf = (e == 0) ? xb.x : (e == 1) ? xb.y : (e == 2) ? xb.z : xb.w;
            acc0.x = __builtin_fmaf(xe, wv.x, acc0.x);
            acc0.y = __builtin_fmaf(xe, wv.y, acc0.y);
            acc0.z = __builtin_fmaf(xe, wv.z, acc0.z);
            acc0.w = __builtin_fmaf(xe, wv.w, acc0.w);
            acc1.x = __builtin_fmaf(xf, wv.x, acc1.x);
            acc1.y = __builtin_fmaf(xf, wv.y, acc1.y);
            acc1.z = __builtin_fmaf(xf, wv.z, acc1.z);
            acc1.w = __builtin_fmaf(xf, wv.w, acc1.w);
        }
    }

    float4 bv = *(const float4*)&bias[gq * 4];
    const int g0 = 4 * gq, q = g0 >> 3, j0 = g0 & 7, cls = q >> 1, qb = q & 1;
    #pragma unroll
    for (int r = 0; r < 2; ++r) {
        int b = b0 + r;
        float4 a = r ? acc1 : acc0;
        size_t base = (((size_t)s * 64 + (b >> 2)) * 64
                      + (b & 3) * 16 + qb * 8 + j0) * 2 + cls;
        xg2[base + 0] = a.x + bv.x;
        xg2[base + 2] = a.y + bv.y;
        xg2[base + 4] = a.z + bv.z;
        xg2[base + 6] = a.w + bv.w;
    }
}

// ======================= Kernel B: fused scan =======================
// 16 lanes/chain, 4 chains/wave, 64 waves. Zero LDS ops; packed-f32 matvecs.
// HB=true: store h1 to hbuf (proj in separate kernel). HB=false: in-scan proj.
template<bool HB>
__global__ __launch_bounds__(64, 1) void lstm_scan(
    const float* __restrict__ xg,
    const float* __restrict__ w_hh0,
    const float* __restrict__ w_ih1, const float* __restrict__ w_hh1,
    const float* __restrict__ b_ih1, const float* __restrict__ b_hh1,
    const float* __restrict__ w_reg, const float* __restrict__ b_reg,
    float* __restrict__ hb, float* __restrict__ out)
{
    const int lt = threadIdx.x;
    const int j  = lt & 7;
    const int b3 = (lt >> 3) & 1;
    const int cc = lt >> 4;
    const bool b3z = (b3 == 0);
    const bool isl = (j == 0);
    const int bid = blockIdx.x;

    const int gA = b3 * 8 + j;
    const int gB = (2 + b3) * 8 + j;
    const float sB_ = b3z ? STANH : SSIG;
    const float aB  = b3z ? 2.0f : 1.0f;
    const float bB  = b3z ? -1.0f : 0.0f;

    v2 w0p[8], wi1p[8], wh1p[8];
    float wrl[8];
    #pragma unroll
    for (int m = 0; m < 8; ++m) {
        int k = j ^ m;
        w0p[m]  = v2{SSIG * w_hh0[gA * 8 + k], sB_ * w_hh0[gB * 8 + k]};
        wi1p[m] = v2{SSIG * w_ih1[gA * 8 + k], sB_ * w_ih1[gB * 8 + k]};
        wh1p[m] = v2{SSIG * w_hh1[gA * 8 + k], sB_ * w_hh1[gB * 8 + k]};
        wrl[m]  = w_reg[b3 * 8 + k];
    }
    const v2 b1p = v2{SSIG * (b_ih1[gA] + b_hh1[gA]), sB_ * (b_ih1[gB] + b_hh1[gB])};
    const float br = b_reg[b3];

    auto tanhc = [](float c) {
        return __builtin_fmaf(2.0f, __builtin_amdgcn_rcpf(
            1.0f + __builtin_amdgcn_exp2f(STANH * c)), -1.0f);
    };
    auto COMBINE2 = [&](float tA, float tB, float& c, float& h) {
        float m  = tA * tB;
        float mr = dppf<ROR8>(m);
        float fa = dppf<ROR8>(tA);
        float ob = dppf<ROR8>(tB);
        float ig = b3z ? m  : mr;
        float f  = b3z ? fa : tA;
        float o  = b3z ? ob : tB;
        c = __builtin_fmaf(f, c, ig);
        h = o * tanhc(c);
    };

    float h0p = 0.f, h1p = 0.f, c0v = 0.f, c1v = 0.f;

    const float* xrow = xg + (size_t)bid * 128;   // +8192 floats per step
    v2 xq[8];
    #pragma unroll
    for (int k = 0; k < 8; ++k) {
        xq[k] = *(const v2*)(xrow + lt * 2);
        xrow += 8192;
    }
    const int hoff = (bid * 4 + cc) * 8 + j;
    const int ooff = (bid * 4 + cc) * 2 + b3;
    float* hrow = hb;        // row s, +2048/step (first store at u=1 -> s=0)
    float* orow = out;       // fallback: row s=u-2, +512/step

    auto STEP = [&](v2& xr, bool l1on, bool rec, bool prj, bool pref) {
        v2 xc = xr;
        if (pref) { xr = *(const v2*)(xrow + lt * 2); xrow += 8192; }

        float r0[8], r1[8];
        r0[0] = h0p;                r1[0] = h1p;
        r0[1] = dppf<QP_X1>(h0p);   r1[1] = dppf<QP_X1>(h1p);
        r0[2] = dppf<QP_X2>(h0p);   r1[2] = dppf<QP_X2>(h1p);
        r0[3] = dppf<QP_X3>(h0p);   r1[3] = dppf<QP_X3>(h1p);
        r0[4] = dppf<ROR4>(h0p);    r1[4] = dppf<ROR4>(h1p);
        r0[5] = dppf<QP_X1>(r0[4]); r1[5] = dppf<QP_X1>(r1[4]);
        r0[6] = dppf<QP_X2>(r0[4]); r1[6] = dppf<QP_X2>(r1[4]);
        r0[7] = dppf<QP_X3>(r0[4]); r1[7] = dppf<QP_X3>(r1[4]);

        v2 a0 = xc, a1 = b1p;
        v2 s1 = wh1p[0] * v2{r1[0], r1[0]};
        #pragma unroll
        for (int m = 0; m < 8; ++m) {
            v2 rm = v2{r0[m], r0[m]};
            a0 = __builtin_elementwise_fma(w0p[m], rm, a0);
            a1 = __builtin_elementwise_fma(wi1p[m], rm, a1);
        }
        #pragma unroll
        for (int m = 1; m < 8; ++m) {
            v2 rm = v2{r1[m], r1[m]};
            s1 = __builtin_elementwise_fma(wh1p[m], rm, s1);
        }
        a1 = a1 + s1;

        v2 e0, e1;
        e0.x = __builtin_amdgcn_exp2f(a0.x);
        e0.y = __builtin_amdgcn_exp2f(a0.y);
        e1.x = __builtin_amdgcn_exp2f(a1.x);
        e1.y = __builtin_amdgcn_exp2f(a1.y);
        e0 = e0 + 1.0f;
        e1 = e1 + 1.0f;
        float tA0 = __builtin_amdgcn_rcpf(e0.x);
        float tB0 = __builtin_fmaf(aB, __builtin_amdgcn_rcpf(e0.y), bB);
        float tA1 = __builtin_amdgcn_rcpf(e1.x);
        float tB1 = __builtin_fmaf(aB, __builtin_amdgcn_rcpf(e1.y), bB);

        if (!HB && prj) {   // projection of step u-2 from r1 = bcast h1(u-2)
            float p = br;
            #pragma unroll
            for (int m = 0; m < 8; ++m) p = __builtin_fmaf(wrl[m], r1[m], p);
            if (isl) orow[ooff] = p;
            orow += 512;
        }
        COMBINE2(tA0, tB0, c0v, h0p);
        if (l1on) {
            COMBINE2(tA1, tB1, c1v, h1p);
            if (HB && rec) { hrow[hoff] = h1p; hrow += 2048; }  // dup-write ok
        }
    };

    // prologue u=0..7
    STEP(xq[0], false, false, false, true);
    STEP(xq[1], true,  true,  false, true);
    #pragma unroll
    for (int k = 2; k < 8; ++k) STEP(xq[k], true, true, true, true);
    // main u=8..503
    for (int tb = 8; tb < 504; tb += 8) {
        #pragma unroll
        for (int k = 0; k < 8; ++k) STEP(xq[k], true, true, true, true);
    }
    // epilogue u=504..511
    #pragma unroll
    for (int k = 0; k < 8; ++k) STEP(xq[k], true, true, true, false);

    // tail: layer1(511) (+ fallback proj rows 510,511)
    {
        float r0[8], r1[8];
        r0[0] = h0p;                r1[0] = h1p;
        r0[1] = dppf<QP_X1>(h0p);   r1[1] = dppf<QP_X1>(h1p);
        r0[2] = dppf<QP_X2>(h0p);   r1[2] = dppf<QP_X2>(h1p);
        r0[3] = dppf<QP_X3>(h0p);   r1[3] = dppf<QP_X3>(h1p);
        r0[4] = dppf<ROR4>(h0p);    r1[4] = dppf<ROR4>(h1p);
        r0[5] = dppf<QP_X1>(r0[4]); r1[5] = dppf<QP_X1>(r1[4]);
        r0[6] = dppf<QP_X2>(r0[4]); r1[6] = dppf<QP_X2>(r1[4]);
        r0[7] = dppf<QP_X3>(r0[4]); r1[7] = dppf<QP_X3>(r1[4]);

        v2 a1 = b1p;
        #pragma unroll
        for (int m = 0; m < 8; ++m) {
            v2 rm = v2{r0[m], r0[m]};
            a1 = __builtin_elementwise_fma(wi1p[m], rm, a1);
        }
        #pragma unroll
        for (int m = 0; m < 8; ++m) {
            v2 rm = v2{r1[m], r1[m]};
            a1 = __builtin_elementwise_fma(wh1p[m], rm, a1);
        }
        float tA1 = __builtin_amdgcn_rcpf(1.0f + __builtin_amdgcn_exp2f(a1.x));
        float tB1 = __builtin_fmaf(aB,
            __builtin_amdgcn_rcpf(1.0f + __builtin_amdgcn_exp2f(a1.y)), bB);

        if (!HB) {
            float p = br;
            #pragma unroll
            for (int m = 0; m < 8; ++m) p = __builtin_fmaf(wrl[m], r1[m], p);
            if (isl) orow[ooff] = p;          // row 510
            orow += 512;
        }
        COMBINE2(tA1, tB1, c1v, h1p);          // h1(511)
        if (HB) {
            hrow[hoff] = h1p;                  // row 511
        } else {
            float r2[8];
            r2[0] = h1p;
            r2[1] = dppf<QP_X1>(h1p);
            r2[2] = dppf<QP_X2>(h1p);
            r2[3] = dppf<QP_X3>(h1p);
            r2[4] = dppf<ROR4>(h1p);
            r2[5] = dppf<QP_X1>(r2[4]);
            r2[6] = dppf<QP_X2>(r2[4]);
            r2[7] = dppf<QP_X3>(r2[4]);
            float p2 = br;
            #pragma unroll
            for (int m = 0; m < 8; ++m) p2 = __builtin_fmaf(wrl[m], r2[m], p2);
            if (isl) orow[ooff] = p2;          // row 511
        }
    }
}

// ======================= Kernel C: projection =======================
__global__ __launch_bounds__(256) void proj_k(
    const float* __restrict__ hb, const float* __restrict__ w_reg,
    const float* __restrict__ b_reg, float* __restrict__ out)
{
    const int s = blockIdx.x, t = threadIdx.x;
    const float* hr = hb + ((size_t)s * B_ + t) * 8;
    float4 h0 = *(const float4*)hr;
    float4 h1 = *(const float4*)(hr + 4);
    float hv[8] = {h0.x, h0.y, h0.z, h0.w, h1.x, h1.y, h1.z, h1.w};
    float p0 = b_reg[0], p1 = b_reg[1];
    #pragma unroll
    for (int m = 0; m < 8; ++m) {
        p0 = __builtin_fmaf(w_reg[m], hv[m], p0);
        p1 = __builtin_fmaf(w_reg[8 + m], hv[m], p1);
    }
    float2 o = {p0, p1};
    *(float2*)(out + ((size_t)s * B_ + t) * 2) = o;
}

extern "C" void kernel_launch(void* const* d_in, const int* in_sizes, int n_in,
                              void* d_out, int out_size, void* d_ws, size_t ws_size,
                              hipStream_t stream) {
    (void)in_sizes; (void)n_in; (void)out_size;
    const float* x     = (const float*)d_in[0];
    const float* w_ih0 = (const float*)d_in[1];
    const float* w_hh0 = (const float*)d_in[2];
    const float* b_ih0 = (const float*)d_in[3];
    const float* b_hh0 = (const float*)d_in[4];
    const float* w_ih1 = (const float*)d_in[5];
    const float* w_hh1 = (const float*)d_in[6];
    const float* b_ih1 = (const float*)d_in[7];
    const float* b_hh1 = (const float*)d_in[8];
    const float* w_reg = (const float*)d_in[9];
    const float* b_reg = (const float*)d_in[10];
    float* out = (float*)d_out;
    float* xg2 = (float*)d_ws;                               // 16 MB
    const size_t XG_BYTES = (size_t)S_ * 64 * 128 * 4;
    const size_t HB_BYTES = (size_t)S_ * B_ * 8 * 4;         // 4 MB
    float* hb = (float*)((char*)d_ws + XG_BYTES);

    xg_gemm<<<2048, 256, 0, stream>>>(x, w_ih0, b_ih0, b_hh0, xg2);
    if (ws_size >= XG_BYTES + HB_BYTES) {
        lstm_scan<true><<<64, 64, 0, stream>>>(xg2, w_hh0, w_ih1, w_hh1,
                                               b_ih1, b_hh1, w_reg, b_reg, hb, out);
        proj_k<<<512, 256, 0, stream>>>(hb, w_reg, b_reg, out);
    } else {
        lstm_scan<false><<<64, 64, 0, stream>>>(xg2, w_hh0, w_ih1, w_hh1,
                                                b_ih1, b_hh1, w_reg, b_reg, xg2, out);
    }
}

// Round 10
// 136.308 us; speedup vs baseline: 2.1752x; 1.1053x over previous
//
#include <hip/hip_runtime.h>

#define S_  512
#define B_  256
#define NIN 180

typedef float v2 __attribute__((ext_vector_type(2)));

#define SSIG  -1.4426950408889634f
#define STANH -2.8853900817779268f

// ---- DPP ctrl encodings (verified on HW r5-r9) ----
#define QP_X1 0xB1
#define QP_X2 0x4E
#define QP_X3 0x1B
#define ROR4  0x124
#define ROR8  0x128

template<int CTRL>
__device__ __forceinline__ float dppf(float x) {
    return __uint_as_float((unsigned)__builtin_amdgcn_update_dpp(
        0, (int)__float_as_uint(x), CTRL, 0xF, 0xF, true));
}

#define ROTS8(h, r) do { \
    r[0] = (h); \
    r[1] = dppf<QP_X1>(h); \
    r[2] = dppf<QP_X2>(h); \
    r[3] = dppf<QP_X3>(h); \
    r[4] = dppf<ROR4>(h); \
    r[5] = dppf<QP_X1>(r[4]); \
    r[6] = dppf<QP_X2>(r[4]); \
    r[7] = dppf<QP_X3>(r[4]); \
} while (0)

// ======================= Kernel A: input GEMM =======================
// Verified layout (r6/r9):
// xg2[(((s*64 + b/4)*64) + (b&3)*16 + (q&1)*8 + (g&7))*2 + (q>>1)] =
//   s(g)*(x[s,b,:]·w_ih0[g,:] + b_ih0[g]+b_hh0[g]),  q = g>>3
// 1024 blocks, 4 rows/thread, depth-2 ring.
__global__ __launch_bounds__(256) void xg_gemm(
    const float* __restrict__ x, const float* __restrict__ w,
    const float* __restrict__ bi, const float* __restrict__ bh,
    float* __restrict__ xg2)
{
    __shared__ float wt[NIN][32];
    __shared__ float bias[32];
    const int tid = threadIdx.x;
    for (int idx = tid; idx < NIN * 32; idx += 256) {
        int g = idx / NIN, i = idx - g * NIN;
        float sc = ((g >> 3) == 2) ? STANH : SSIG;
        wt[i][g] = sc * w[idx];
    }
    if (tid < 32) {
        float sc = ((tid >> 3) == 2) ? STANH : SSIG;
        bias[tid] = sc * (bi[tid] + bh[tid]);
    }
    __syncthreads();

    const int rg = tid >> 3;          // 0..31 -> 4 rows each
    const int gq = tid & 7;
    const int s  = blockIdx.x >> 1;
    const int b0 = (blockIdx.x & 1) * 128 + rg * 4;
    const float* xr = x + ((size_t)s * B_ + b0) * NIN;

    float4 acc[4];
    #pragma unroll
    for (int r = 0; r < 4; ++r) acc[r] = float4{0.f, 0.f, 0.f, 0.f};

    float4 rv[2][4];
    #pragma unroll
    for (int r = 0; r < 4; ++r) {
        rv[0][r] = *(const float4*)(xr + (size_t)r * NIN + 0);
        rv[1][r] = *(const float4*)(xr + (size_t)r * NIN + 4);
    }

    #pragma unroll
    for (int ii = 0; ii < 45; ++ii) {
        const int sl = ii & 1;
        float4 xa[4];
        #pragma unroll
        for (int r = 0; r < 4; ++r) xa[r] = rv[sl][r];
        if (ii < 43) {
            #pragma unroll
            for (int r = 0; r < 4; ++r)
                rv[sl][r] = *(const float4*)(xr + (size_t)r * NIN + 4 * (ii + 2));
        }
        #pragma unroll
        for (int e = 0; e < 4; ++e) {
            float4 wv = *(const float4*)&wt[4 * ii + e][gq * 4];
            #pragma unroll
            for (int r = 0; r < 4; ++r) {
                float xe = (e == 0) ? xa[r].x : (e == 1) ? xa[r].y
                         : (e == 2) ? xa[r].z : xa[r].w;
                acc[r].x = __builtin_fmaf(xe, wv.x, acc[r].x);
                acc[r].y = __builtin_fmaf(xe, wv.y, acc[r].y);
                acc[r].z = __builtin_fmaf(xe, wv.z, acc[r].z);
                acc[r].w = __builtin_fmaf(xe, wv.w, acc[r].w);
            }
        }
    }

    float4 bv = *(const float4*)&bias[gq * 4];
    const int g0 = 4 * gq, q = g0 >> 3, j0 = g0 & 7, cls = q >> 1, qb = q & 1;
    #pragma unroll
    for (int r = 0; r < 4; ++r) {
        int b = b0 + r;
        size_t base = (((size_t)s * 64 + (b >> 2)) * 64
                      + (b & 3) * 16 + qb * 8 + j0) * 2 + cls;
        xg2[base + 0] = acc[r].x + bv.x;
        xg2[base + 2] = acc[r].y + bv.y;
        xg2[base + 4] = acc[r].z + bv.z;
        xg2[base + 6] = acc[r].w + bv.w;
    }
}

// ======================= Kernel B: 2-wave scan =======================
// Block = 128 threads = 2 waves, 4 chains. Wave0 = layer0 producer,
// wave1 = layer1+projection consumer. Handoff: a1p (= b1 + Wih1·h0) via
// double-buffered LDS, one barrier/step. B lags 2 steps; proj lags 3.
__global__ __launch_bounds__(128, 1) void lstm_scan(
    const float* __restrict__ xg,
    const float* __restrict__ w_hh0,
    const float* __restrict__ w_ih1, const float* __restrict__ w_hh1,
    const float* __restrict__ b_ih1, const float* __restrict__ b_hh1,
    const float* __restrict__ w_reg, const float* __restrict__ b_reg,
    float* __restrict__ out)
{
    __shared__ float a1buf[2][128];

    const int lt = threadIdx.x & 63;
    const int j  = lt & 7;
    const int b3 = (lt >> 3) & 1;
    const int cc = lt >> 4;
    const bool b3z = (b3 == 0);
    const int bid = blockIdx.x;            // 0..63

    const int gA = b3 * 8 + j;             // i or f (sigmoid)
    const int gB = (2 + b3) * 8 + j;       // g or o (tanh / sigmoid)
    const float sB_ = b3z ? STANH : SSIG;
    const float aB  = b3z ? 2.0f : 1.0f;
    const float bB  = b3z ? -1.0f : 0.0f;

    auto COMBINE2 = [&](float tA, float tB, float& c, float& h) {
        float m  = tA * tB;
        float mr = dppf<ROR8>(m);
        float fa = dppf<ROR8>(tA);
        float ob = dppf<ROR8>(tB);
        float ig = b3z ? m  : mr;
        float f  = b3z ? fa : tA;
        float o  = b3z ? ob : tB;
        c = __builtin_fmaf(f, c, ig);
        float th = __builtin_fmaf(2.0f, __builtin_amdgcn_rcpf(
            1.0f + __builtin_amdgcn_exp2f(STANH * c)), -1.0f);
        h = o * th;
    };

    if (threadIdx.x < 64) {
        // ================= wave A: layer 0 =================
        v2 w0p[8], wi1p[8];
        #pragma unroll
        for (int m = 0; m < 8; ++m) {
            int k = j ^ m;
            w0p[m]  = v2{SSIG * w_hh0[gA * 8 + k], sB_ * w_hh0[gB * 8 + k]};
            wi1p[m] = v2{SSIG * w_ih1[gA * 8 + k], sB_ * w_ih1[gB * 8 + k]};
        }
        const v2 b1p = v2{SSIG * (b_ih1[gA] + b_hh1[gA]),
                          sB_  * (b_ih1[gB] + b_hh1[gB])};

        float h0p = 0.f, c0v = 0.f;
        const float* xrow = xg + (size_t)bid * 128;
        v2 xq[8];
        #pragma unroll
        for (int k2 = 0; k2 < 8; ++k2) {
            xq[k2] = *(const v2*)(xrow + lt * 2);
            xrow += 8192;
        }

        auto ASTEP = [&](v2& xr, int slot, bool pref) {
            v2 xc = xr;
            if (pref) { xr = *(const v2*)(xrow + lt * 2); xrow += 8192; }
            float r0[8];
            ROTS8(h0p, r0);
            v2 a0 = xc, a1p = b1p;
            #pragma unroll
            for (int m = 0; m < 8; ++m) {
                v2 rm = v2{r0[m], r0[m]};
                a0  = __builtin_elementwise_fma(w0p[m], rm, a0);
                a1p = __builtin_elementwise_fma(wi1p[m], rm, a1p);
            }
            *(v2*)&a1buf[slot][lt * 2] = a1p;
            float eA = __builtin_amdgcn_exp2f(a0.x);
            float eB = __builtin_amdgcn_exp2f(a0.y);
            float tA = __builtin_amdgcn_rcpf(1.0f + eA);
            float tB = __builtin_fmaf(aB, __builtin_amdgcn_rcpf(1.0f + eB), bB);
            COMBINE2(tA, tB, c0v, h0p);
            __syncthreads();
        };

        // u = 0..7
        #pragma unroll
        for (int k2 = 0; k2 < 8; ++k2) ASTEP(xq[k2], k2 & 1, true);
        // u = 8..503
        for (int tb = 8; tb < 504; tb += 8) {
            #pragma unroll
            for (int k2 = 0; k2 < 8; ++k2) ASTEP(xq[k2], k2 & 1, true);
        }
        // u = 504..511 (no prefetch)
        #pragma unroll
        for (int k2 = 0; k2 < 8; ++k2) ASTEP(xq[k2], k2 & 1, false);

        // tail: a1p(511) from h0(511) -> slot 0 (u=512)
        {
            float r0[8];
            ROTS8(h0p, r0);
            v2 a1p = b1p;
            #pragma unroll
            for (int m = 0; m < 8; ++m) {
                v2 rm = v2{r0[m], r0[m]};
                a1p = __builtin_elementwise_fma(wi1p[m], rm, a1p);
            }
            *(v2*)&a1buf[0][lt * 2] = a1p;
            __syncthreads();                       // A barrier #513
        }
    } else {
        // ============ wave B: layer 1 + projection ============
        v2 wh1p[8];
        float wrl[8];
        #pragma unroll
        for (int m = 0; m < 8; ++m) {
            int k = j ^ m;
            wh1p[m] = v2{SSIG * w_hh1[gA * 8 + k], sB_ * w_hh1[gB * 8 + k]};
            wrl[m]  = w_reg[b3 * 8 + k];
        }
        const float br  = b_reg[b3];
        const bool isl  = (j == 0);
        const int  ooff = (bid * 4 + cc) * 2 + b3;

        float h1p = 0.f, c1v = 0.f;

        auto BSTEP = [&](int slot, bool dostore, int yrow) {
            v2 a1 = *(const v2*)&a1buf[slot][lt * 2];
            float r1[8];
            ROTS8(h1p, r1);
            #pragma unroll
            for (int m = 0; m < 8; ++m) {
                v2 rm = v2{r1[m], r1[m]};
                a1 = __builtin_elementwise_fma(wh1p[m], rm, a1);
            }
            float p = br;
            #pragma unroll
            for (int m = 0; m < 8; ++m) p = __builtin_fmaf(wrl[m], r1[m], p);
            float eA = __builtin_amdgcn_exp2f(a1.x);
            float eB = __builtin_amdgcn_exp2f(a1.y);
            float tA = __builtin_amdgcn_rcpf(1.0f + eA);
            float tB = __builtin_fmaf(aB, __builtin_amdgcn_rcpf(1.0f + eB), bB);
            if (dostore && isl) out[(size_t)yrow * 512 + ooff] = p;
            COMBINE2(tA, tB, c1v, h1p);
        };

        __syncthreads();                           // B barrier #1 (A u=0)
        __syncthreads();                           // B barrier #2 (A u=1)
        for (int u = 2; u < 512; ++u) {            // computes h1(u-2), y(u-3)
            BSTEP((u - 1) & 1, u >= 3, u - 3);
            __syncthreads();
        }
        BSTEP(1, true, 509);                       // h1(510), y(509)
        __syncthreads();                           // B barrier #513 (A tail)
        BSTEP(0, true, 510);                       // h1(511), y(510)
        {
            float r1[8];
            ROTS8(h1p, r1);                        // bcast h1(511)
            float p = br;
            #pragma unroll
            for (int m = 0; m < 8; ++m) p = __builtin_fmaf(wrl[m], r1[m], p);
            if (isl) out[(size_t)511 * 512 + ooff] = p;   // y(511)
        }
    }
}

extern "C" void kernel_launch(void* const* d_in, const int* in_sizes, int n_in,
                              void* d_out, int out_size, void* d_ws, size_t ws_size,
                              hipStream_t stream) {
    (void)in_sizes; (void)n_in; (void)out_size; (void)ws_size;
    const float* x     = (const float*)d_in[0];
    const float* w_ih0 = (const float*)d_in[1];
    const float* w_hh0 = (const float*)d_in[2];
    const float* b_ih0 = (const float*)d_in[3];
    const float* b_hh0 = (const float*)d_in[4];
    const float* w_ih1 = (const float*)d_in[5];
    const float* w_hh1 = (const float*)d_in[6];
    const float* b_ih1 = (const float*)d_in[7];
    const float* b_hh1 = (const float*)d_in[8];
    const float* w_reg = (const float*)d_in[9];
    const float* b_reg = (const float*)d_in[10];
    float* out = (float*)d_out;
    float* xg2 = (float*)d_ws;   // 512*64*128*4 = 16 MB scratch

    xg_gemm<<<1024, 256, 0, stream>>>(x, w_ih0, b_ih0, b_hh0, xg2);
    lstm_scan<<<64, 128, 0, stream>>>(xg2, w_hh0, w_ih1, w_hh1, b_ih1, b_hh1,
                                      w_reg, b_reg, out);
}

// Round 11
// 129.568 us; speedup vs baseline: 2.2884x; 1.0520x over previous
//
#include <hip/hip_runtime.h>

#define S_  512
#define B_  256
#define NIN 180

typedef float v2 __attribute__((ext_vector_type(2)));

#define SSIG  -1.4426950408889634f
#define STANH -2.8853900817779268f

// ---- DPP ctrl encodings (verified on HW r5-r10) ----
#define QP_X1 0xB1
#define QP_X2 0x4E
#define QP_X3 0x1B
#define ROR4  0x124
#define ROR8  0x128

template<int CTRL>
__device__ __forceinline__ float dppf(float x) {
    return __uint_as_float((unsigned)__builtin_amdgcn_update_dpp(
        0, (int)__float_as_uint(x), CTRL, 0xF, 0xF, true));
}

#define ROTS8(h, r) do { \
    r[0] = (h); \
    r[1] = dppf<QP_X1>(h); \
    r[2] = dppf<QP_X2>(h); \
    r[3] = dppf<QP_X3>(h); \
    r[4] = dppf<ROR4>(h); \
    r[5] = dppf<QP_X1>(r[4]); \
    r[6] = dppf<QP_X2>(r[4]); \
    r[7] = dppf<QP_X3>(r[4]); \
} while (0)

// ======================= Kernel A: input GEMM =======================
// Permuted wt columns so each (row b) output is ONE float4:
// col c = t*4+e  <->  gate = (t>>2)*8 + (t&3)*2 + (e>>1) + (e&1)*16
// float4 at ((s*64+(b>>2))*128) + (b&3)*32 + (t>>2)*16 + (t&3)*4
// == scan layout: pair (j,cls0),(j,cls1) at ...+ qb*16 + j*2 + cls.
__global__ __launch_bounds__(256) void xg_gemm(
    const float* __restrict__ x, const float* __restrict__ w,
    const float* __restrict__ bi, const float* __restrict__ bh,
    float* __restrict__ xg2)
{
    __shared__ float wt[NIN][32];   // permuted + pre-scaled
    __shared__ float bias[32];
    const int tid = threadIdx.x;
    for (int idx = tid; idx < NIN * 32; idx += 256) {
        int c = idx / NIN, i = idx - c * NIN;
        int t = c >> 2, e = c & 3;
        int g = (t >> 2) * 8 + (t & 3) * 2 + (e >> 1) + ((e & 1) << 4);
        float sc = ((g >> 3) == 2) ? STANH : SSIG;
        wt[i][c] = sc * w[g * NIN + i];
    }
    if (tid < 32) {
        int c = tid, t = c >> 2, e = c & 3;
        int g = (t >> 2) * 8 + (t & 3) * 2 + (e >> 1) + ((e & 1) << 4);
        float sc = ((g >> 3) == 2) ? STANH : SSIG;
        bias[c] = sc * (bi[g] + bh[g]);
    }
    __syncthreads();

    const int rg = tid >> 3;          // 0..31 -> 8 rows each
    const int t8 = tid & 7;           // permuted gate-quad
    const int s  = blockIdx.x;        // grid 512 = S
    const int b0 = rg * 8;
    const float* xr = x + ((size_t)s * B_ + b0) * NIN;

    v2 acc[8][2];
    #pragma unroll
    for (int r = 0; r < 8; ++r) { acc[r][0] = v2{0.f, 0.f}; acc[r][1] = v2{0.f, 0.f}; }

    float4 xb[3][8];
    #pragma unroll
    for (int d = 0; d < 3; ++d)
        #pragma unroll
        for (int r = 0; r < 8; ++r)
            xb[d][r] = *(const float4*)(xr + (size_t)r * NIN + 4 * d);

    auto GSTEP = [&](int ii, int d, bool pref) {
        float4 xn[8];
        if (pref) {
            #pragma unroll
            for (int r = 0; r < 8; ++r)
                xn[r] = *(const float4*)(xr + (size_t)r * NIN + 4 * (ii + 3));
        }
        #pragma unroll
        for (int e = 0; e < 4; ++e) {
            float4 wv = *(const float4*)&wt[4 * ii + e][t8 * 4];
            v2 wlo = v2{wv.x, wv.y}, whi = v2{wv.z, wv.w};
            #pragma unroll
            for (int r = 0; r < 8; ++r) {
                float xe = (e == 0) ? xb[d][r].x : (e == 1) ? xb[d][r].y
                         : (e == 2) ? xb[d][r].z : xb[d][r].w;
                v2 xv = v2{xe, xe};
                acc[r][0] = __builtin_elementwise_fma(wlo, xv, acc[r][0]);
                acc[r][1] = __builtin_elementwise_fma(whi, xv, acc[r][1]);
            }
        }
        if (pref) {
            #pragma unroll
            for (int r = 0; r < 8; ++r) xb[d][r] = xn[r];
        }
    };

    for (int r = 0; r < 14; ++r) {
        GSTEP(3 * r + 0, 0, true);
        GSTEP(3 * r + 1, 1, true);
        GSTEP(3 * r + 2, 2, true);
    }
    GSTEP(42, 0, false);
    GSTEP(43, 1, false);
    GSTEP(44, 2, false);

    float4 bv = *(const float4*)&bias[t8 * 4];
    const int toff = (t8 >> 2) * 16 + (t8 & 3) * 4;
    #pragma unroll
    for (int r = 0; r < 8; ++r) {
        int b = b0 + r;
        float4 o;
        o.x = acc[r][0].x + bv.x;
        o.y = acc[r][0].y + bv.y;
        o.z = acc[r][1].x + bv.z;
        o.w = acc[r][1].y + bv.w;
        size_t base = ((size_t)s * 64 + (b >> 2)) * 128 + (b & 3) * 32 + toff;
        *(float4*)(xg2 + base) = o;
    }
}

// ======================= Kernel B: 2-wave scan, 4-step phases ========
// Wave0 (layer0) writes a1p(u-1) to slot (u-1)&15 of a 16-slot LDS ring;
// one __syncthreads per 4 steps (129 barriers total). Wave1 (layer1+proj)
// lags 8 steps. Verified: B phase p reads slots (4p-8..4p-5)&15, A writes
// (4p-1..4p+2)&15 -> disjoint; data written >=1 phase earlier, overwritten
// >=2 phases later.
__global__ __launch_bounds__(128, 1) void lstm_scan(
    const float* __restrict__ xg,
    const float* __restrict__ w_hh0,
    const float* __restrict__ w_ih1, const float* __restrict__ w_hh1,
    const float* __restrict__ b_ih1, const float* __restrict__ b_hh1,
    const float* __restrict__ w_reg, const float* __restrict__ b_reg,
    float* __restrict__ out)
{
    __shared__ float abuf[16][128];

    const int lt = threadIdx.x & 63;
    const int j  = lt & 7;
    const int b3 = (lt >> 3) & 1;
    const int cc = lt >> 4;
    const bool b3z = (b3 == 0);
    const int bid = blockIdx.x;            // 0..63

    const int gA = b3 * 8 + j;
    const int gB = (2 + b3) * 8 + j;
    const float sB_ = b3z ? STANH : SSIG;
    const float aB  = b3z ? 2.0f : 1.0f;
    const float bB  = b3z ? -1.0f : 0.0f;

    auto COMBINE2 = [&](float tA, float tB, float& c, float& h) {
        float m  = tA * tB;
        float mr = dppf<ROR8>(m);
        float fa = dppf<ROR8>(tA);
        float ob = dppf<ROR8>(tB);
        float ig = b3z ? m  : mr;
        float f  = b3z ? fa : tA;
        float o  = b3z ? ob : tB;
        c = __builtin_fmaf(f, c, ig);
        float th = __builtin_fmaf(2.0f, __builtin_amdgcn_rcpf(
            1.0f + __builtin_amdgcn_exp2f(STANH * c)), -1.0f);
        h = o * th;
    };

    if (threadIdx.x < 64) {
        // ================= wave A: layer 0 =================
        v2 w0p[8], wi1p[8];
        #pragma unroll
        for (int m = 0; m < 8; ++m) {
            int k = j ^ m;
            w0p[m]  = v2{SSIG * w_hh0[gA * 8 + k], sB_ * w_hh0[gB * 8 + k]};
            wi1p[m] = v2{SSIG * w_ih1[gA * 8 + k], sB_ * w_ih1[gB * 8 + k]};
        }
        const v2 b1p = v2{SSIG * (b_ih1[gA] + b_hh1[gA]),
                          sB_  * (b_ih1[gB] + b_hh1[gB])};

        float h0p = 0.f, c0v = 0.f;
        const float* xrow = xg + (size_t)bid * 128;
        v2 xq[8];
        #pragma unroll
        for (int k2 = 0; k2 < 8; ++k2) {
            xq[k2] = *(const v2*)(xrow + lt * 2);
            xrow += 8192;
        }

        auto ASTEP = [&](v2& xr, int slot, bool store, bool pref) {
            v2 xc = xr;
            if (pref) { xr = *(const v2*)(xrow + lt * 2); xrow += 8192; }
            float r0[8];
            ROTS8(h0p, r0);
            v2 a0 = xc, a1p = b1p;
            #pragma unroll
            for (int m = 0; m < 8; ++m) {
                v2 rm = v2{r0[m], r0[m]};
                a0  = __builtin_elementwise_fma(w0p[m], rm, a0);
                a1p = __builtin_elementwise_fma(wi1p[m], rm, a1p);
            }
            if (store) *(v2*)&abuf[slot][lt * 2] = a1p;
            float eA = __builtin_amdgcn_exp2f(a0.x);
            float eB = __builtin_amdgcn_exp2f(a0.y);
            float tA = __builtin_amdgcn_rcpf(1.0f + eA);
            float tB = __builtin_fmaf(aB, __builtin_amdgcn_rcpf(1.0f + eB), bB);
            COMBINE2(tA, tB, c0v, h0p);
        };

        // prologue: steps 0..7 (2 phases); step u stores slot (u-1)&15
        ASTEP(xq[0], 0, false, true);
        ASTEP(xq[1], 0, true, true);
        ASTEP(xq[2], 1, true, true);
        ASTEP(xq[3], 2, true, true);
        __syncthreads();
        ASTEP(xq[4], 3, true, true);
        ASTEP(xq[5], 4, true, true);
        ASTEP(xq[6], 5, true, true);
        ASTEP(xq[7], 6, true, true);
        __syncthreads();
        // main: steps 8..503, 16-step body (slot pattern (7+k)&15)
        for (int m = 0; m < 31; ++m) {
            #pragma unroll
            for (int k = 0; k < 16; ++k) {
                ASTEP(xq[k & 7], (7 + k) & 15, true, true);
                if ((k & 3) == 3) __syncthreads();
            }
        }
        // epilogue: steps 504..511 (no prefetch)
        #pragma unroll
        for (int k = 0; k < 8; ++k) {
            ASTEP(xq[k], (7 + k) & 15, true, false);
            if ((k & 3) == 3) __syncthreads();
        }
        // tail: a1p(511) from h0(511) -> slot 15
        {
            float r0[8];
            ROTS8(h0p, r0);
            v2 a1p = b1p;
            #pragma unroll
            for (int m = 0; m < 8; ++m) {
                v2 rm = v2{r0[m], r0[m]};
                a1p = __builtin_elementwise_fma(wi1p[m], rm, a1p);
            }
            *(v2*)&abuf[15][lt * 2] = a1p;
            __syncthreads();                       // barrier #129
        }
    } else {
        // ============ wave B: layer 1 + projection ============
        v2 wh1p[8];
        float wrl[8];
        #pragma unroll
        for (int m = 0; m < 8; ++m) {
            int k = j ^ m;
            wh1p[m] = v2{SSIG * w_hh1[gA * 8 + k], sB_ * w_hh1[gB * 8 + k]};
            wrl[m]  = w_reg[b3 * 8 + k];
        }
        const float br  = b_reg[b3];
        const bool isl  = (j == 0);
        float* op = out + (size_t)(bid * 4 + cc) * 2 + b3;   // row 0

        float h1p = 0.f, c1v = 0.f;

        auto BSTEP = [&](int slot, bool doproj) {
            v2 a1 = *(const v2*)&abuf[slot][lt * 2];
            float r1[8];
            ROTS8(h1p, r1);
            #pragma unroll
            for (int m = 0; m < 8; ++m) {
                v2 rm = v2{r1[m], r1[m]};
                a1 = __builtin_elementwise_fma(wh1p[m], rm, a1);
            }
            float eA = __builtin_amdgcn_exp2f(a1.x);
            float eB = __builtin_amdgcn_exp2f(a1.y);
            float tA = __builtin_amdgcn_rcpf(1.0f + eA);
            float tB = __builtin_fmaf(aB, __builtin_amdgcn_rcpf(1.0f + eB), bB);
            if (doproj) {      // y(v-1) from r1 = bcast h1(v-1)
                float p = br;
                #pragma unroll
                for (int m = 0; m < 8; ++m) p = __builtin_fmaf(wrl[m], r1[m], p);
                if (isl) *op = p;
                op += 512;
            }
            COMBINE2(tA, tB, c1v, h1p);
        };

        __syncthreads();       // phase 0
        __syncthreads();       // phase 1
        // m=0 block: v = 0..15 (v=0 has no proj)
        #pragma unroll
        for (int k = 0; k < 16; ++k) {
            BSTEP(k, k != 0);
            if ((k & 3) == 3) __syncthreads();
        }
        // m=1..30: v = 16..495
        for (int m = 1; m < 31; ++m) {
            #pragma unroll
            for (int k = 0; k < 16; ++k) {
                BSTEP(k, true);
                if ((k & 3) == 3) __syncthreads();
            }
        }
        // v = 496..503 (2 phases)
        #pragma unroll
        for (int k = 0; k < 8; ++k) {
            BSTEP(k, true);
            if ((k & 3) == 3) __syncthreads();
        }
        __syncthreads();       // tail barrier (#129): slot 15 = a1p(511)
        #pragma unroll
        for (int k = 8; k < 16; ++k) BSTEP(k, true);   // v = 504..511
        // final: y(511) from h1(511)
        {
            float r1[8];
            ROTS8(h1p, r1);
            float p = br;
            #pragma unroll
            for (int m = 0; m < 8; ++m) p = __builtin_fmaf(wrl[m], r1[m], p);
            if (isl) *op = p;
        }
    }
}

extern "C" void kernel_launch(void* const* d_in, const int* in_sizes, int n_in,
                              void* d_out, int out_size, void* d_ws, size_t ws_size,
                              hipStream_t stream) {
    (void)in_sizes; (void)n_in; (void)out_size; (void)ws_size;
    const float* x     = (const float*)d_in[0];
    const float* w_ih0 = (const float*)d_in[1];
    const float* w_hh0 = (const float*)d_in[2];
    const float* b_ih0 = (const float*)d_in[3];
    const float* b_hh0 = (const float*)d_in[4];
    const float* w_ih1 = (const float*)d_in[5];
    const float* w_hh1 = (const float*)d_in[6];
    const float* b_ih1 = (const float*)d_in[7];
    const float* b_hh1 = (const float*)d_in[8];
    const float* w_reg = (const float*)d_in[9];
    const float* b_reg = (const float*)d_in[10];
    float* out = (float*)d_out;
    float* xg2 = (float*)d_ws;   // 512*64*128*4 = 16 MB scratch

    xg_gemm<<<512, 256, 0, stream>>>(x, w_ih0, b_ih0, b_hh0, xg2);
    lstm_scan<<<64, 128, 0, stream>>>(xg2, w_hh0, w_ih1, w_hh1, b_ih1, b_hh1,
                                      w_reg, b_reg, out);
}

// Round 12
// 111.791 us; speedup vs baseline: 2.6523x; 1.1590x over previous
//
#include <hip/hip_runtime.h>

#define S_  512
#define B_  256
#define NIN 180

typedef float v2 __attribute__((ext_vector_type(2)));

#define SSIG  -1.4426950408889634f
#define STANH -2.8853900817779268f

// ---- DPP ctrl encodings (verified on HW r5-r11) ----
#define QP_X1 0xB1
#define QP_X2 0x4E
#define QP_X3 0x1B
#define ROR4  0x124
#define ROR8  0x128

template<int CTRL>
__device__ __forceinline__ float dppf(float x) {
    return __uint_as_float((unsigned)__builtin_amdgcn_update_dpp(
        0, (int)__float_as_uint(x), CTRL, 0xF, 0xF, true));
}

#define ROTS8(h, r) do { \
    r[0] = (h); \
    r[1] = dppf<QP_X1>(h); \
    r[2] = dppf<QP_X2>(h); \
    r[3] = dppf<QP_X3>(h); \
    r[4] = dppf<ROR4>(h); \
    r[5] = dppf<QP_X1>(r[4]); \
    r[6] = dppf<QP_X2>(r[4]); \
    r[7] = dppf<QP_X3>(r[4]); \
} while (0)

// ======================= Kernel A: input GEMM =======================
// Permuted wt columns (r11-verified): col c=t*4+e <-> gate
// g=(t>>2)*8+(t&3)*2+(e>>1)+(e&1)*16; float4 store at
// ((s*64+(b>>2))*128)+(b&3)*32+(t>>2)*16+(t&3)*4.
// 1024 blocks, 4 rows/thread, depth-3 ring (VGPR-safe), pk_fma.
__global__ __launch_bounds__(256) void xg_gemm(
    const float* __restrict__ x, const float* __restrict__ w,
    const float* __restrict__ bi, const float* __restrict__ bh,
    float* __restrict__ xg2)
{
    __shared__ float wt[NIN][32];
    __shared__ float bias[32];
    const int tid = threadIdx.x;
    for (int idx = tid; idx < NIN * 32; idx += 256) {
        int c = idx / NIN, i = idx - c * NIN;
        int t = c >> 2, e = c & 3;
        int g = (t >> 2) * 8 + (t & 3) * 2 + (e >> 1) + ((e & 1) << 4);
        float sc = ((g >> 3) == 2) ? STANH : SSIG;
        wt[i][c] = sc * w[g * NIN + i];
    }
    if (tid < 32) {
        int c = tid, t = c >> 2, e = c & 3;
        int g = (t >> 2) * 8 + (t & 3) * 2 + (e >> 1) + ((e & 1) << 4);
        float sc = ((g >> 3) == 2) ? STANH : SSIG;
        bias[c] = sc * (bi[g] + bh[g]);
    }
    __syncthreads();

    const int rg = tid >> 3;              // 0..31 -> 4 rows each
    const int t8 = tid & 7;
    const int s  = blockIdx.x >> 1;
    const int b0 = (blockIdx.x & 1) * 128 + rg * 4;
    const float* xr = x + ((size_t)s * B_ + b0) * NIN;

    v2 acc[4][2];
    #pragma unroll
    for (int r = 0; r < 4; ++r) { acc[r][0] = v2{0.f,0.f}; acc[r][1] = v2{0.f,0.f}; }

    float4 xb[3][4];
    #pragma unroll
    for (int d = 0; d < 3; ++d)
        #pragma unroll
        for (int r = 0; r < 4; ++r)
            xb[d][r] = *(const float4*)(xr + (size_t)r * NIN + 4 * d);

    auto GSTEP = [&](int ii, int d, bool pref) {
        float4 xn[4];
        if (pref) {
            #pragma unroll
            for (int r = 0; r < 4; ++r)
                xn[r] = *(const float4*)(xr + (size_t)r * NIN + 4 * (ii + 3));
        }
        #pragma unroll
        for (int e = 0; e < 4; ++e) {
            float4 wv = *(const float4*)&wt[4 * ii + e][t8 * 4];
            v2 wlo = v2{wv.x, wv.y}, whi = v2{wv.z, wv.w};
            #pragma unroll
            for (int r = 0; r < 4; ++r) {
                float xe = (e == 0) ? xb[d][r].x : (e == 1) ? xb[d][r].y
                         : (e == 2) ? xb[d][r].z : xb[d][r].w;
                v2 xv = v2{xe, xe};
                acc[r][0] = __builtin_elementwise_fma(wlo, xv, acc[r][0]);
                acc[r][1] = __builtin_elementwise_fma(whi, xv, acc[r][1]);
            }
        }
        if (pref) {
            #pragma unroll
            for (int r = 0; r < 4; ++r) xb[d][r] = xn[r];
        }
    };

    for (int r = 0; r < 14; ++r) {
        GSTEP(3 * r + 0, 0, true);
        GSTEP(3 * r + 1, 1, true);
        GSTEP(3 * r + 2, 2, true);
    }
    GSTEP(42, 0, false);
    GSTEP(43, 1, false);
    GSTEP(44, 2, false);

    float4 bv = *(const float4*)&bias[t8 * 4];
    const int toff = (t8 >> 2) * 16 + (t8 & 3) * 4;
    #pragma unroll
    for (int r = 0; r < 4; ++r) {
        int b = b0 + r;
        float4 o;
        o.x = acc[r][0].x + bv.x;
        o.y = acc[r][0].y + bv.y;
        o.z = acc[r][1].x + bv.z;
        o.w = acc[r][1].y + bv.w;
        size_t base = ((size_t)s * 64 + (b >> 2)) * 128 + (b & 3) * 32 + toff;
        *(float4*)(xg2 + base) = o;
    }
}

// ======================= Kernel B: 3-wave scan =======================
// Block = 192 thr = 3 waves: A1 (layer0 recurrence, stores h0 ring),
// A2 (a1p = b1 + Wih1*h0, h0-ring -> a1p-ring), B (layer1 recurrence,
// stores h1 to hbuf; proj in separate kernel when HB).
// Phases of 4 steps; every wave executes exactly 129 __syncthreads.
template<bool HB>
__global__ __launch_bounds__(192, 1) void lstm_scan(
    const float* __restrict__ xg,
    const float* __restrict__ w_hh0,
    const float* __restrict__ w_ih1, const float* __restrict__ w_hh1,
    const float* __restrict__ b_ih1, const float* __restrict__ b_hh1,
    const float* __restrict__ w_reg, const float* __restrict__ b_reg,
    float* __restrict__ hb, float* __restrict__ out)
{
    __shared__ float ring0[16][64];    // h0(u) at slot u&15
    __shared__ float ring1[16][128];   // a1p(u) (v2) at slot u&15

    const int tid = threadIdx.x;
    const int wid = tid >> 6;          // 0=A1, 1=A2, 2=B
    const int lt  = tid & 63;
    const int j   = lt & 7;
    const int b3  = (lt >> 3) & 1;
    const int cc  = lt >> 4;
    const bool b3z = (b3 == 0);
    const int bid = blockIdx.x;        // 0..63

    const int gA = b3 * 8 + j;
    const int gB = (2 + b3) * 8 + j;
    const float sB_ = b3z ? STANH : SSIG;
    const float aB  = b3z ? 2.0f : 1.0f;
    const float bB  = b3z ? -1.0f : 0.0f;

    auto COMBINE2 = [&](float tA, float tB, float& c, float& h) {
        float m  = tA * tB;
        float mr = dppf<ROR8>(m);
        float fa = dppf<ROR8>(tA);
        float ob = dppf<ROR8>(tB);
        float ig = b3z ? m  : mr;
        float f  = b3z ? fa : tA;
        float o  = b3z ? ob : tB;
        c = __builtin_fmaf(f, c, ig);
        float th = __builtin_fmaf(2.0f, __builtin_amdgcn_rcpf(
            1.0f + __builtin_amdgcn_exp2f(STANH * c)), -1.0f);
        h = o * th;
    };

    if (wid == 0) {
        // =============== wave A1: layer-0 recurrence ===============
        v2 w0p[8];
        #pragma unroll
        for (int m = 0; m < 8; ++m) {
            int k = j ^ m;
            w0p[m] = v2{SSIG * w_hh0[gA * 8 + k], sB_ * w_hh0[gB * 8 + k]};
        }
        float h0p = 0.f, c0v = 0.f;

        const float* xbase = xg + (size_t)bid * 128 + lt * 2;
        v2 xq[8];
        #pragma unroll
        for (int k = 0; k < 8; ++k) xq[k] = *(const v2*)(xbase + (size_t)k * 8192);

        // 64 bodies of 8 steps; ring slot base = (hh&1)*8; prefetch row (u+8)&511
        for (int hh = 0; hh < 64; ++hh) {
            const float* pre = xbase + (size_t)((8 * hh + 8) & 511) * 8192;
            const int sb8 = (hh & 1) * 8;
            #pragma unroll
            for (int k = 0; k < 8; ++k) {
                v2 xc = xq[k];
                xq[k] = *(const v2*)(pre + (size_t)k * 8192);
                float r0[8];
                ROTS8(h0p, r0);
                v2 a0L = __builtin_elementwise_fma(w0p[0], v2{r0[0], r0[0]}, xc);
                v2 a0H = w0p[4] * v2{r0[4], r0[4]};
                #pragma unroll
                for (int m = 1; m < 4; ++m) {
                    a0L = __builtin_elementwise_fma(w0p[m], v2{r0[m], r0[m]}, a0L);
                    a0H = __builtin_elementwise_fma(w0p[m + 4], v2{r0[m + 4], r0[m + 4]}, a0H);
                }
                v2 a0 = a0L + a0H;
                float eA = __builtin_amdgcn_exp2f(a0.x);
                float eB = __builtin_amdgcn_exp2f(a0.y);
                float tA = __builtin_amdgcn_rcpf(1.0f + eA);
                float tB = __builtin_fmaf(aB, __builtin_amdgcn_rcpf(1.0f + eB), bB);
                COMBINE2(tA, tB, c0v, h0p);
                ring0[sb8 + k][lt] = h0p;
                if (k == 3 || k == 7) __syncthreads();
            }
        }
        __syncthreads();                          // #129
    } else if (wid == 1) {
        // =============== wave A2: a1p = b1 + Wih1*h0 ===============
        v2 wi1p[8];
        #pragma unroll
        for (int m = 0; m < 8; ++m) {
            int k = j ^ m;
            wi1p[m] = v2{SSIG * w_ih1[gA * 8 + k], sB_ * w_ih1[gB * 8 + k]};
        }
        const v2 b1p = v2{SSIG * (b_ih1[gA] + b_hh1[gA]),
                          sB_  * (b_ih1[gB] + b_hh1[gB])};

        __syncthreads();                          // #1 (end of phase 0)
        for (int p = 1; p <= 128; ++p) {
            const int sb = ((p - 1) & 3) * 4;
            float h0v[4];
            #pragma unroll
            for (int k = 0; k < 4; ++k) h0v[k] = ring0[sb + k][lt];
            #pragma unroll
            for (int k = 0; k < 4; ++k) {
                float r0[8];
                ROTS8(h0v[k], r0);
                v2 a = __builtin_elementwise_fma(wi1p[0], v2{r0[0], r0[0]}, b1p);
                #pragma unroll
                for (int m = 1; m < 8; ++m)
                    a = __builtin_elementwise_fma(wi1p[m], v2{r0[m], r0[m]}, a);
                *(v2*)&ring1[sb + k][lt * 2] = a;
            }
            __syncthreads();                      // #1+p
        }
    } else {
        // =============== wave B: layer-1 recurrence ===============
        v2 wh1p[8];
        float wrl[8];
        #pragma unroll
        for (int m = 0; m < 8; ++m) {
            int k = j ^ m;
            wh1p[m] = v2{SSIG * w_hh1[gA * 8 + k], sB_ * w_hh1[gB * 8 + k]};
            wrl[m]  = w_reg[b3 * 8 + k];
        }
        const float br  = b_reg[b3];
        const bool isl  = (j == 0);
        float* hrow = hb + (size_t)(bid * 4 + cc) * 8 + j;   // +2048/step
        float* op   = out + (size_t)(bid * 4 + cc) * 2 + b3; // +512/step (!HB)
        float h1p = 0.f, c1v = 0.f;

        auto BODY4 = [&](int p, bool last) {
            const int sb = ((p - 2) & 3) * 4;
            v2 a1in[4];
            #pragma unroll
            for (int k = 0; k < 4; ++k) a1in[k] = *(const v2*)&ring1[sb + k][lt * 2];
            #pragma unroll
            for (int k = 0; k < 4; ++k) {
                float r1[8];
                ROTS8(h1p, r1);
                v2 aL = __builtin_elementwise_fma(wh1p[0], v2{r1[0], r1[0]}, a1in[k]);
                v2 aH = wh1p[4] * v2{r1[4], r1[4]};
                #pragma unroll
                for (int m = 1; m < 4; ++m) {
                    aL = __builtin_elementwise_fma(wh1p[m], v2{r1[m], r1[m]}, aL);
                    aH = __builtin_elementwise_fma(wh1p[m + 4], v2{r1[m + 4], r1[m + 4]}, aH);
                }
                v2 a1 = aL + aH;
                float eA = __builtin_amdgcn_exp2f(a1.x);
                float eB = __builtin_amdgcn_exp2f(a1.y);
                float tA = __builtin_amdgcn_rcpf(1.0f + eA);
                float tB = __builtin_fmaf(aB, __builtin_amdgcn_rcpf(1.0f + eB), bB);
                if (!HB) {
                    // proj of step w-1 from r1 = bcast h1(w-1), skip w==0
                    if (p > 2 || k > 0) {
                        float pp = br;
                        #pragma unroll
                        for (int m = 0; m < 8; ++m) pp = __builtin_fmaf(wrl[m], r1[m], pp);
                        if (isl) *op = pp;
                        op += 512;
                    }
                }
                COMBINE2(tA, tB, c1v, h1p);
                if (HB) {
                    if (b3z) *hrow = h1p;
                    hrow += 2048;
                }
            }
            if (!last) __syncthreads();
        };

        __syncthreads();                          // #1
        __syncthreads();                          // #2
        for (int p = 2; p <= 128; ++p) BODY4(p, false);   // syncs #3..#129
        BODY4(129, true);                          // steps 508..511, no sync
        if (!HB) {
            float r1[8];
            ROTS8(h1p, r1);                        // h1(511)
            float pp = br;
            #pragma unroll
            for (int m = 0; m < 8; ++m) pp = __builtin_fmaf(wrl[m], r1[m], pp);
            if (isl) *op = pp;                     // y(511)
        }
    }
}

// ======================= Kernel C: projection (r9-verified) ==========
__global__ __launch_bounds__(256) void proj_k(
    const float* __restrict__ hbuf, const float* __restrict__ w_reg,
    const float* __restrict__ b_reg, float* __restrict__ out)
{
    const int s = blockIdx.x, t = threadIdx.x;
    const float* hr = hbuf + ((size_t)s * B_ + t) * 8;
    float4 h0 = *(const float4*)hr;
    float4 h1 = *(const float4*)(hr + 4);
    float hv[8] = {h0.x, h0.y, h0.z, h0.w, h1.x, h1.y, h1.z, h1.w};
    float p0 = b_reg[0], p1 = b_reg[1];
    #pragma unroll
    for (int m = 0; m < 8; ++m) {
        p0 = __builtin_fmaf(w_reg[m], hv[m], p0);
        p1 = __builtin_fmaf(w_reg[8 + m], hv[m], p1);
    }
    float2 o = {p0, p1};
    *(float2*)(out + ((size_t)s * B_ + t) * 2) = o;
}

extern "C" void kernel_launch(void* const* d_in, const int* in_sizes, int n_in,
                              void* d_out, int out_size, void* d_ws, size_t ws_size,
                              hipStream_t stream) {
    (void)in_sizes; (void)n_in; (void)out_size;
    const float* x     = (const float*)d_in[0];
    const float* w_ih0 = (const float*)d_in[1];
    const float* w_hh0 = (const float*)d_in[2];
    const float* b_ih0 = (const float*)d_in[3];
    const float* b_hh0 = (const float*)d_in[4];
    const float* w_ih1 = (const float*)d_in[5];
    const float* w_hh1 = (const float*)d_in[6];
    const float* b_ih1 = (const float*)d_in[7];
    const float* b_hh1 = (const float*)d_in[8];
    const float* w_reg = (const float*)d_in[9];
    const float* b_reg = (const float*)d_in[10];
    float* out = (float*)d_out;
    float* xg2 = (float*)d_ws;                            // 16 MB
    const size_t XG_BYTES = (size_t)S_ * 64 * 128 * 4;
    const size_t HB_BYTES = (size_t)S_ * B_ * 8 * 4;      // 4 MB
    float* hbuf = (float*)((char*)d_ws + XG_BYTES);

    xg_gemm<<<1024, 256, 0, stream>>>(x, w_ih0, b_ih0, b_hh0, xg2);
    if (ws_size >= XG_BYTES + HB_BYTES) {
        lstm_scan<true><<<64, 192, 0, stream>>>(xg2, w_hh0, w_ih1, w_hh1,
                                                b_ih1, b_hh1, w_reg, b_reg,
                                                hbuf, out);
        proj_k<<<512, 256, 0, stream>>>(hbuf, w_reg, b_reg, out);
    } else {
        lstm_scan<false><<<64, 192, 0, stream>>>(xg2, w_hh0, w_ih1, w_hh1,
                                                 b_ih1, b_hh1, w_reg, b_reg,
                                                 xg2, out);
    }
}